// Round 1
// baseline (174.497 us; speedup 1.0000x reference)
//
#include <hip/hip_runtime.h>
#include <hip/hip_bf16.h>
#include <math.h>

#define E_ 128
#define H_ 128
#define B_ 8
#define U_ 128
#define T_ 256
#define LDK 136  // padded K stride (elements) for W2T in LDS: +8 bf16 = 2-way bank alias (free)

typedef short short8 __attribute__((ext_vector_type(8)));
typedef float floatx4 __attribute__((ext_vector_type(4)));

__device__ __forceinline__ unsigned short f2bf(float f) {
    __hip_bfloat16 b = __float2bfloat16(f);
    union { __hip_bfloat16 b; unsigned short u; } cv;
    cv.b = b;
    return cv.u;
}

__device__ __forceinline__ float gelu_exact(float x) {
    return 0.5f * x * (1.0f + erff(x * 0.70710678118654752f));
}

// ---------------- Stage 1: tiny GEMMs into workspace -----------------------
// blocks 0..1023            : hu[b,u,:] = ue[b,u,:]@W1u + ge[b,:]@W1g + b1
// blocks 1024..3071         : ht[b,t,:] = te[b,t,:]@W1t
// block  3072               : W2T bf16 (n-major) for MFMA B-operand staging
__global__ __launch_bounds__(128) void stage1_kernel(
    const float* __restrict__ ue, const float* __restrict__ te,
    const float* __restrict__ ge, const float* __restrict__ W1,
    const float* __restrict__ b1, const float* __restrict__ W2,
    float* __restrict__ hu_ws, float* __restrict__ ht_ws,
    unsigned short* __restrict__ w2t_ws)
{
    const int blk = blockIdx.x;
    const int tid = threadIdx.x;
    __shared__ float row_s[E_];
    __shared__ float ge_s[E_];

    if (blk < B_ * U_) {
        const int b = blk >> 7;
        row_s[tid] = ue[blk * E_ + tid];
        ge_s[tid]  = ge[b * E_ + tid];
        __syncthreads();
        float acc = b1[tid];
        const float* __restrict__ W1u = W1;
        const float* __restrict__ W1g = W1 + 2 * E_ * H_;
        #pragma unroll 8
        for (int e = 0; e < E_; e++) acc += row_s[e] * W1u[e * H_ + tid];
        #pragma unroll 8
        for (int e = 0; e < E_; e++) acc += ge_s[e] * W1g[e * H_ + tid];
        hu_ws[blk * H_ + tid] = acc;
    } else if (blk < B_ * U_ + B_ * T_) {
        const int r = blk - B_ * U_;
        row_s[tid] = te[r * E_ + tid];
        __syncthreads();
        float acc = 0.0f;
        const float* __restrict__ W1t = W1 + E_ * H_;
        #pragma unroll 8
        for (int e = 0; e < E_; e++) acc += row_s[e] * W1t[e * H_ + tid];
        ht_ws[r * H_ + tid] = acc;
    } else {
        // transpose W2 (k-major) -> W2T (n-major), cast to bf16
        for (int i = tid; i < H_ * H_; i += 128) {
            const int k = i >> 7, n = i & 127;
            w2t_ws[n * H_ + k] = f2bf(W2[i]);
        }
    }
}

// ---------------- Stage 2: fused gelu -> @W2 -> gelu -> @W3 ----------------
// block = 256 threads (4 waves); tile = one (b,u) x 64 t-rows.
// wave w owns A-rows t0+16w..+15; 8 column tiles of 16 -> 32 f32 accs/lane.
__global__ __launch_bounds__(256) void stage2_kernel(
    const float* __restrict__ hu_ws, const float* __restrict__ ht_ws,
    const unsigned short* __restrict__ w2t_ws,
    const float* __restrict__ b2, const float* __restrict__ W3,
    const float* __restrict__ b3, float* __restrict__ out)
{
    __shared__ unsigned short w2s[H_][LDK];
    __shared__ float hu_s[H_];
    __shared__ float b2_s[H_];
    __shared__ float w3_s[H_];

    const int tid = threadIdx.x;
    const int t0 = blockIdx.x * 64;
    const int u  = blockIdx.y;
    const int b  = blockIdx.z;

    // stage W2T bf16 -> LDS (padded rows); coalesced ushort4 copies
    for (int g = tid; g < (H_ * H_) / 4; g += 256) {
        const int n = g >> 5;          // 32 ushort4 groups per 128-row
        const int c = (g & 31) * 4;
        *(ushort4*)(&w2s[n][c]) = *(const ushort4*)(w2t_ws + n * H_ + c);
    }
    if (tid < H_) {
        hu_s[tid] = hu_ws[((b << 7) + u) * H_ + tid];
        b2_s[tid] = b2[tid];
        w3_s[tid] = W3[tid];
    }
    __syncthreads();

    const int wave = tid >> 6;
    const int lane = tid & 63;
    const int quad = lane >> 4;
    const int l16  = lane & 15;

    // A-operand row for this lane (m = lane&15); quad indexes k-chunk
    const int trow = t0 + wave * 16 + l16;
    const float* __restrict__ htrow = ht_ws + ((size_t)(b * T_) + trow) * H_;

    floatx4 acc[8];
    #pragma unroll
    for (int nt = 0; nt < 8; nt++) acc[nt] = (floatx4){0.f, 0.f, 0.f, 0.f};

    #pragma unroll
    for (int kk = 0; kk < 4; kk++) {
        const int k0 = kk * 32 + quad * 8;
        const float4 v0 = *(const float4*)(htrow + k0);
        const float4 v1 = *(const float4*)(htrow + k0 + 4);
        short8 afrag;
        afrag[0] = (short)f2bf(gelu_exact(v0.x + hu_s[k0 + 0]));
        afrag[1] = (short)f2bf(gelu_exact(v0.y + hu_s[k0 + 1]));
        afrag[2] = (short)f2bf(gelu_exact(v0.z + hu_s[k0 + 2]));
        afrag[3] = (short)f2bf(gelu_exact(v0.w + hu_s[k0 + 3]));
        afrag[4] = (short)f2bf(gelu_exact(v1.x + hu_s[k0 + 4]));
        afrag[5] = (short)f2bf(gelu_exact(v1.y + hu_s[k0 + 5]));
        afrag[6] = (short)f2bf(gelu_exact(v1.z + hu_s[k0 + 6]));
        afrag[7] = (short)f2bf(gelu_exact(v1.w + hu_s[k0 + 7]));
        #pragma unroll
        for (int nt = 0; nt < 8; nt++) {
            const int n = nt * 16 + l16;          // B-operand col (n = lane&15)
            short8 bfrag = *(const short8*)(&w2s[n][k0]);
            acc[nt] = __builtin_amdgcn_mfma_f32_16x16x32_bf16(afrag, bfrag, acc[nt], 0, 0, 0);
        }
    }

    // epilogue: +b2, gelu, *W3, reduce over 128 cols per row, +b3
    const float b3v = b3[0];
    float psum[4] = {0.f, 0.f, 0.f, 0.f};
    #pragma unroll
    for (int nt = 0; nt < 8; nt++) {
        const int n = nt * 16 + l16;
        const float bb = b2_s[n];
        const float ww = w3_s[n];
        #pragma unroll
        for (int r = 0; r < 4; r++) {
            const float v = gelu_exact(acc[nt][r] + bb);
            psum[r] += v * ww;
        }
    }
    // C/D rows = quad*4+r, cols spread over l16 -> reduce across the 16-lane group
    #pragma unroll
    for (int m = 8; m >= 1; m >>= 1) {
        #pragma unroll
        for (int r = 0; r < 4; r++) psum[r] += __shfl_xor(psum[r], m, 64);
    }
    if (l16 == 0) {
        const int trowbase = t0 + wave * 16 + quad * 4;
        float4 o = make_float4(psum[0] + b3v, psum[1] + b3v, psum[2] + b3v, psum[3] + b3v);
        *(float4*)(out + (size_t)((b << 7) + u) * T_ + trowbase) = o;
    }
}

extern "C" void kernel_launch(void* const* d_in, const int* in_sizes, int n_in,
                              void* d_out, int out_size, void* d_ws, size_t ws_size,
                              hipStream_t stream)
{
    const float* ue = (const float*)d_in[0];
    const float* te = (const float*)d_in[1];
    const float* ge = (const float*)d_in[2];
    const float* W1 = (const float*)d_in[3];
    const float* b1 = (const float*)d_in[4];
    const float* W2 = (const float*)d_in[5];
    const float* b2 = (const float*)d_in[6];
    const float* W3 = (const float*)d_in[7];
    const float* b3 = (const float*)d_in[8];
    float* out = (float*)d_out;

    char* ws = (char*)d_ws;
    float* hu_ws = (float*)ws;                                   // 1024*128*4 = 512 KB
    float* ht_ws = (float*)(ws + 512 * 1024);                    // 2048*128*4 = 1 MB
    unsigned short* w2t_ws = (unsigned short*)(ws + 1536 * 1024); // 16384*2 = 32 KB

    stage1_kernel<<<dim3(B_ * U_ + B_ * T_ + 1), dim3(128), 0, stream>>>(
        ue, te, ge, W1, b1, W2, hu_ws, ht_ws, w2t_ws);
    stage2_kernel<<<dim3(T_ / 64, U_, B_), dim3(256), 0, stream>>>(
        hu_ws, ht_ws, w2t_ws, b2, W3, b3, out);
}

// Round 2
// 133.116 us; speedup vs baseline: 1.3109x; 1.3109x over previous
//
#include <hip/hip_runtime.h>
#include <hip/hip_bf16.h>
#include <math.h>

#define E_ 128
#define H_ 128
#define B_ 8
#define U_ 128
#define T_ 256
#define LDK 136  // padded K stride (elements) for W2T in LDS

typedef short short8 __attribute__((ext_vector_type(8)));
typedef unsigned short ushort8_t __attribute__((ext_vector_type(8)));
typedef float floatx4 __attribute__((ext_vector_type(4)));

__device__ __forceinline__ unsigned short f2bf(float f) {
    union { __hip_bfloat16 b; unsigned short u; } cv;
    cv.b = __float2bfloat16(f);
    return cv.u;
}

// tanh-form gelu: x * sigmoid(1.59577x + 0.0713548x^3); max |err| vs erf-gelu ~3e-4
__device__ __forceinline__ float gelu_fast(float x) {
    float x2 = x * x;
    float p = x * __builtin_fmaf(x2, 0.0713548163f, 1.5957691216f);
    float e = __expf(-p);                       // v_mul + v_exp_f32
    return x * __builtin_amdgcn_rcpf(1.0f + e); // v_add + v_rcp_f32 + v_mul
}

// ------------- Stage 1 main: tiled fp32 GEMM (ue@W1u, te@W1t) --------------
// 96 blocks x 256 threads; each block: 32 rows x 128 cols.
// blocks 0..31  -> rows of ue (1024), W1u, out hu_ws
// blocks 32..95 -> rows of te (2048), W1t, out ht_ws
__global__ __launch_bounds__(256) void stage1_main(
    const float* __restrict__ ue, const float* __restrict__ te,
    const float* __restrict__ W1,
    float* __restrict__ hu_ws, float* __restrict__ ht_ws)
{
    __shared__ float a_s[32][128];
    const int blk = blockIdx.x;
    const int tid = threadIdx.x;

    const float* __restrict__ A;
    const float* __restrict__ W;
    float* __restrict__ out;
    int rowbase;
    if (blk < 32) { A = ue; W = W1;           out = hu_ws; rowbase = blk * 32; }
    else          { A = te; W = W1 + E_ * H_; out = ht_ws; rowbase = (blk - 32) * 32; }

    // stage A tile (32x128 f32 = 16 KB), coalesced float4
    const float4* __restrict__ Av = (const float4*)(A + rowbase * E_);
    #pragma unroll
    for (int i = 0; i < 4; i++) {
        const int idx = tid + i * 256;
        ((float4*)&a_s[0][0])[idx] = Av[idx];
    }
    __syncthreads();

    const int n = tid & 127;
    const int g = tid >> 7;  // row group: rows g*16 .. g*16+15

    float acc[16];
    #pragma unroll
    for (int r = 0; r < 16; r++) acc[r] = 0.0f;

    for (int ec = 0; ec < 128; ec += 4) {
        const float w0 = W[(ec + 0) * H_ + n];
        const float w1 = W[(ec + 1) * H_ + n];
        const float w2 = W[(ec + 2) * H_ + n];
        const float w3 = W[(ec + 3) * H_ + n];
        #pragma unroll
        for (int r = 0; r < 16; r++) {
            const float4 a4 = *(const float4*)(&a_s[g * 16 + r][ec]);  // wave-broadcast
            acc[r] = __builtin_fmaf(a4.x, w0, acc[r]);
            acc[r] = __builtin_fmaf(a4.y, w1, acc[r]);
            acc[r] = __builtin_fmaf(a4.z, w2, acc[r]);
            acc[r] = __builtin_fmaf(a4.w, w3, acc[r]);
        }
    }
    #pragma unroll
    for (int r = 0; r < 16; r++)
        out[(rowbase + g * 16 + r) * H_ + n] = acc[r];
}

// ------------- Stage 1 misc: gu = ge@W1g + b1 (8 rows) + W2T bf16 ----------
__global__ __launch_bounds__(128) void stage1_misc(
    const float* __restrict__ ge, const float* __restrict__ W1,
    const float* __restrict__ b1, const float* __restrict__ W2,
    float* __restrict__ gu_ws, unsigned short* __restrict__ w2t_ws)
{
    const int blk = blockIdx.x;
    const int tid = threadIdx.x;
    if (blk < B_) {
        __shared__ float ge_s[E_];
        ge_s[tid] = ge[blk * E_ + tid];
        __syncthreads();
        const float* __restrict__ W1g = W1 + 2 * E_ * H_;
        float acc = b1[tid];
        #pragma unroll 8
        for (int e = 0; e < E_; e++) acc = __builtin_fmaf(ge_s[e], W1g[e * H_ + tid], acc);
        gu_ws[blk * H_ + tid] = acc;
    } else {
        // transpose W2 (k-major) -> W2T (n-major), cast to bf16
        for (int i = tid; i < H_ * H_; i += 128) {
            const int k = i >> 7, n = i & 127;
            w2t_ws[n * H_ + k] = f2bf(W2[i]);
        }
    }
}

// ---------------- Stage 2: fused gelu -> @W2 -> gelu -> @W3 ----------------
__global__ __launch_bounds__(256) void stage2_kernel(
    const float* __restrict__ hu_ws, const float* __restrict__ ht_ws,
    const float* __restrict__ gu_ws,
    const unsigned short* __restrict__ w2t_ws,
    const float* __restrict__ b2, const float* __restrict__ W3,
    const float* __restrict__ b3, float* __restrict__ out)
{
    __shared__ unsigned short w2s[H_][LDK];
    __shared__ float hu_s[H_];
    __shared__ float b2_s[H_];
    __shared__ float w3_s[H_];

    const int tid = threadIdx.x;
    const int t0 = blockIdx.x * 64;
    const int u  = blockIdx.y;
    const int b  = blockIdx.z;

    // stage W2T bf16 -> LDS (padded rows); 16B copies
    for (int g = tid; g < (H_ * H_) / 8; g += 256) {
        const int n = g >> 4;
        const int c = (g & 15) * 8;
        *(ushort8_t*)(&w2s[n][c]) = *(const ushort8_t*)(w2t_ws + n * H_ + c);
    }
    if (tid < H_) {
        hu_s[tid] = hu_ws[((b << 7) + u) * H_ + tid] + gu_ws[(b << 7) + tid];
        b2_s[tid] = b2[tid];
        w3_s[tid] = W3[tid];
    }
    __syncthreads();

    const int wave = tid >> 6;
    const int lane = tid & 63;
    const int quad = lane >> 4;
    const int l16  = lane & 15;

    const int trow = t0 + wave * 16 + l16;   // A-row m = lane&15
    const float* __restrict__ htrow = ht_ws + ((size_t)(b * T_) + trow) * H_;

    floatx4 acc[8];
    #pragma unroll
    for (int nt = 0; nt < 8; nt++) acc[nt] = (floatx4){0.f, 0.f, 0.f, 0.f};

    #pragma unroll
    for (int kk = 0; kk < 4; kk++) {
        const int k0 = kk * 32 + quad * 8;
        const float4 v0 = *(const float4*)(htrow + k0);
        const float4 v1 = *(const float4*)(htrow + k0 + 4);
        const float4 h0 = *(const float4*)(&hu_s[k0]);      // ds_read_b128 broadcast x4
        const float4 h1 = *(const float4*)(&hu_s[k0 + 4]);
        short8 afrag;
        afrag[0] = (short)f2bf(gelu_fast(v0.x + h0.x));
        afrag[1] = (short)f2bf(gelu_fast(v0.y + h0.y));
        afrag[2] = (short)f2bf(gelu_fast(v0.z + h0.z));
        afrag[3] = (short)f2bf(gelu_fast(v0.w + h0.w));
        afrag[4] = (short)f2bf(gelu_fast(v1.x + h1.x));
        afrag[5] = (short)f2bf(gelu_fast(v1.y + h1.y));
        afrag[6] = (short)f2bf(gelu_fast(v1.z + h1.z));
        afrag[7] = (short)f2bf(gelu_fast(v1.w + h1.w));
        #pragma unroll
        for (int nt = 0; nt < 8; nt++) {
            const int n = nt * 16 + l16;
            short8 bfrag = *(const short8*)(&w2s[n][k0]);
            acc[nt] = __builtin_amdgcn_mfma_f32_16x16x32_bf16(afrag, bfrag, acc[nt], 0, 0, 0);
        }
    }

    // epilogue: +b2, gelu, *W3, reduce 128 cols/row, +b3
    const float b3v = b3[0];
    float psum[4] = {0.f, 0.f, 0.f, 0.f};
    #pragma unroll
    for (int nt = 0; nt < 8; nt++) {
        const int n = nt * 16 + l16;
        const float bb = b2_s[n];
        const float ww = w3_s[n];
        #pragma unroll
        for (int r = 0; r < 4; r++) {
            psum[r] += gelu_fast(acc[nt][r] + bb) * ww;
        }
    }
    #pragma unroll
    for (int m = 8; m >= 1; m >>= 1) {
        #pragma unroll
        for (int r = 0; r < 4; r++) psum[r] += __shfl_xor(psum[r], m, 64);
    }
    if (l16 == 0) {
        const int trowbase = t0 + wave * 16 + quad * 4;
        float4 o = make_float4(psum[0] + b3v, psum[1] + b3v, psum[2] + b3v, psum[3] + b3v);
        *(float4*)(out + (size_t)((b << 7) + u) * T_ + trowbase) = o;
    }
}

extern "C" void kernel_launch(void* const* d_in, const int* in_sizes, int n_in,
                              void* d_out, int out_size, void* d_ws, size_t ws_size,
                              hipStream_t stream)
{
    const float* ue = (const float*)d_in[0];
    const float* te = (const float*)d_in[1];
    const float* ge = (const float*)d_in[2];
    const float* W1 = (const float*)d_in[3];
    const float* b1 = (const float*)d_in[4];
    const float* W2 = (const float*)d_in[5];
    const float* b2 = (const float*)d_in[6];
    const float* W3 = (const float*)d_in[7];
    const float* b3 = (const float*)d_in[8];
    float* out = (float*)d_out;

    char* ws = (char*)d_ws;
    float* hu_ws = (float*)ws;                                    // 512 KB
    float* ht_ws = (float*)(ws + 512 * 1024);                     // 1 MB
    unsigned short* w2t_ws = (unsigned short*)(ws + 1536 * 1024); // 32 KB
    float* gu_ws = (float*)(ws + 1568 * 1024);                    // 4 KB

    stage1_main<<<dim3(96), dim3(256), 0, stream>>>(ue, te, W1, hu_ws, ht_ws);
    stage1_misc<<<dim3(B_ + 1), dim3(128), 0, stream>>>(ge, W1, b1, W2, gu_ws, w2t_ws);
    stage2_kernel<<<dim3(T_ / 64, U_, B_), dim3(256), 0, stream>>>(
        hu_ws, ht_ws, gu_ws, w2t_ws, b2, W3, b3, out);
}

// Round 3
// 102.875 us; speedup vs baseline: 1.6962x; 1.2940x over previous
//
#include <hip/hip_runtime.h>
#include <hip/hip_bf16.h>
#include <math.h>

#define E_ 128
#define H_ 128
#define B_ 8
#define U_ 128
#define T_ 256
#define LDK 136  // padded bf16 leading dim: row stride 272B -> 2-way bank alias (free, m136)

typedef short short8 __attribute__((ext_vector_type(8)));
typedef unsigned short ushort8_t __attribute__((ext_vector_type(8)));
typedef float floatx4 __attribute__((ext_vector_type(4)));

__device__ __forceinline__ unsigned short f2bf(float f) {
    union { __hip_bfloat16 b; unsigned short u; } cv;
    cv.b = __float2bfloat16(f);
    return cv.u;
}

// tanh-form gelu: x * sigmoid(1.59577x + 0.0713548x^3); |err| vs erf-gelu <~3e-4.
// exp2-folded: sigmoid(p) = 1/(1+exp2(-p*log2e)) with log2e folded into coeffs.
__device__ __forceinline__ float gelu_fast(float x) {
    float x2 = x * x;
    float p = x * __builtin_fmaf(x2, 0.1029407583f, 2.3022586210f);  // coeffs * log2(e)
    float e = __builtin_amdgcn_exp2f(-p);
    return x * __builtin_amdgcn_rcpf(1.0f + e);
}

// ---------------- Stage 1 (one kernel, 36 blocks) ---------------------------
// blk 0..7  : hu[128 rows] = ue_tile @ W1u      (bf16 MFMA)
// blk 8..23 : ht[128 rows] = te_tile @ W1t      (bf16 MFMA)
// blk 24..27: gu[2 rows]   = ge @ W1g + b1      (fp32 VALU)
// blk 28..35: w2t bf16 transpose (2048 elems each)
__global__ __launch_bounds__(256) void stage1_kernel(
    const float* __restrict__ ue, const float* __restrict__ te,
    const float* __restrict__ ge, const float* __restrict__ W1,
    const float* __restrict__ b1, const float* __restrict__ W2,
    float* __restrict__ hu_ws, float* __restrict__ ht_ws,
    float* __restrict__ gu_ws, unsigned short* __restrict__ w2t_ws)
{
    const int blk = blockIdx.x;
    const int tid = threadIdx.x;

    if (blk < 24) {
        __shared__ unsigned short a_s[128][LDK];  // A tile, bf16, [row][k]
        __shared__ unsigned short w_s[128][LDK];  // W tile, bf16, [n][k] (transposed)
        const float* __restrict__ A;
        const float* __restrict__ W;
        float* __restrict__ outp;
        if (blk < 8) { A = ue + (size_t)blk * 128 * E_;        W = W1;            outp = hu_ws + (size_t)blk * 128 * H_; }
        else         { A = te + (size_t)(blk - 8) * 128 * E_;  W = W1 + E_ * H_;  outp = ht_ws + (size_t)(blk - 8) * 128 * H_; }

        // stage A: 4096 float4 coalesced, convert to bf16
        const float4* __restrict__ Av = (const float4*)A;
        #pragma unroll
        for (int i = 0; i < 16; i++) {
            const int v = tid + i * 256;
            const int row = v >> 5, c = (v & 31) * 4;
            const float4 f = Av[v];
            ushort4 u4 = make_ushort4(f2bf(f.x), f2bf(f.y), f2bf(f.z), f2bf(f.w));
            *(ushort4*)(&a_s[row][c]) = u4;
        }
        // stage W transposed: read [k][n] float4, write [n][k] bf16 scalars
        const float4* __restrict__ Wv = (const float4*)W;
        #pragma unroll
        for (int i = 0; i < 16; i++) {
            const int v = tid + i * 256;
            const int k = v >> 5, n = (v & 31) * 4;
            const float4 f = Wv[v];
            w_s[n + 0][k] = f2bf(f.x);
            w_s[n + 1][k] = f2bf(f.y);
            w_s[n + 2][k] = f2bf(f.z);
            w_s[n + 3][k] = f2bf(f.w);
        }
        __syncthreads();

        const int wave = tid >> 6, lane = tid & 63;
        const int quad = lane >> 4, l16 = lane & 15;
        const int r0 = wave * 32 + l16;

        floatx4 acc[2][8];
        #pragma unroll
        for (int m = 0; m < 2; m++)
            #pragma unroll
            for (int nt = 0; nt < 8; nt++) acc[m][nt] = (floatx4){0.f, 0.f, 0.f, 0.f};

        #pragma unroll
        for (int kk = 0; kk < 4; kk++) {
            const int k0 = kk * 32 + quad * 8;
            short8 af0 = *(const short8*)(&a_s[r0][k0]);
            short8 af1 = *(const short8*)(&a_s[r0 + 16][k0]);
            #pragma unroll
            for (int nt = 0; nt < 8; nt++) {
                short8 bf = *(const short8*)(&w_s[nt * 16 + l16][k0]);
                acc[0][nt] = __builtin_amdgcn_mfma_f32_16x16x32_bf16(af0, bf, acc[0][nt], 0, 0, 0);
                acc[1][nt] = __builtin_amdgcn_mfma_f32_16x16x32_bf16(af1, bf, acc[1][nt], 0, 0, 0);
            }
        }
        // write: C/D layout row=quad*4+r, col=nt*16+l16
        #pragma unroll
        for (int m = 0; m < 2; m++) {
            const int rowb = wave * 32 + m * 16 + quad * 4;
            #pragma unroll
            for (int nt = 0; nt < 8; nt++) {
                const int col = nt * 16 + l16;
                #pragma unroll
                for (int r = 0; r < 4; r++)
                    outp[(size_t)(rowb + r) * H_ + col] = acc[m][nt][r];
            }
        }
    } else if (blk < 28) {
        // gu = ge @ W1g + b1, two rows per block
        __shared__ float ge_s[2][E_];
        const int rbase = (blk - 24) * 2;
        const int half = tid >> 7, n = tid & 127;
        ge_s[half][n] = ge[(rbase + half) * E_ + n];
        __syncthreads();
        const float* __restrict__ W1g = W1 + 2 * E_ * H_;
        float acc = b1[n];
        #pragma unroll 8
        for (int e = 0; e < E_; e++)
            acc = __builtin_fmaf(ge_s[half][e], W1g[e * H_ + n], acc);
        gu_ws[(rbase + half) * H_ + n] = acc;
    } else {
        // W2 (k-major) -> w2t (n-major) bf16; coalesced writes
        const int base = (blk - 28) * 2048;
        #pragma unroll
        for (int i = 0; i < 8; i++) {
            const int o = base + tid + i * 256;
            const int n = o >> 7, k = o & 127;
            w2t_ws[o] = f2bf(W2[k * H_ + n]);
        }
    }
}

// ---------------- Stage 2: fused gelu -> @W2 -> gelu -> @W3 ----------------
// 4 waves/block; each wave: 32 rows (two 16-row m-tiles), B-frag reused x2.
// Block covers 128 t-rows; grid (T/128, U, B) = 2048 blocks.
__global__ __launch_bounds__(256, 4) void stage2_kernel(
    const float* __restrict__ hu_ws, const float* __restrict__ ht_ws,
    const float* __restrict__ gu_ws,
    const unsigned short* __restrict__ w2t_ws,
    const float* __restrict__ b2, const float* __restrict__ W3,
    const float* __restrict__ b3, float* __restrict__ out)
{
    __shared__ unsigned short w2s[H_][LDK];
    __shared__ float hu_s[H_];
    __shared__ float b2_s[H_];
    __shared__ float w3_s[H_];

    const int tid = threadIdx.x;
    const int t0 = blockIdx.x * 128;
    const int u  = blockIdx.y;
    const int b  = blockIdx.z;

    // stage W2T bf16 -> LDS (16B copies)
    for (int g = tid; g < (H_ * H_) / 8; g += 256) {
        const int n = g >> 4;
        const int c = (g & 15) * 8;
        *(ushort8_t*)(&w2s[n][c]) = *(const ushort8_t*)(w2t_ws + n * H_ + c);
    }
    if (tid < H_) {
        hu_s[tid] = hu_ws[((b << 7) + u) * H_ + tid] + gu_ws[b * H_ + tid];
        b2_s[tid] = b2[tid];
        w3_s[tid] = W3[tid];
    }
    __syncthreads();

    const int wave = tid >> 6, lane = tid & 63;
    const int quad = lane >> 4, l16 = lane & 15;

    const int rowA = t0 + wave * 32 + l16;   // m-tile 0 row for this lane
    const float* __restrict__ htrow0 = ht_ws + ((size_t)(b * T_) + rowA) * H_;
    const float* __restrict__ htrow1 = htrow0 + 16 * H_;

    floatx4 acc[2][8];
    #pragma unroll
    for (int m = 0; m < 2; m++)
        #pragma unroll
        for (int nt = 0; nt < 8; nt++) acc[m][nt] = (floatx4){0.f, 0.f, 0.f, 0.f};

    #pragma unroll
    for (int kk = 0; kk < 4; kk++) {
        const int k0 = kk * 32 + quad * 8;
        const float4 h0 = *(const float4*)(&hu_s[k0]);
        const float4 h1 = *(const float4*)(&hu_s[k0 + 4]);
        const float4 a00 = *(const float4*)(htrow0 + k0);
        const float4 a01 = *(const float4*)(htrow0 + k0 + 4);
        const float4 a10 = *(const float4*)(htrow1 + k0);
        const float4 a11 = *(const float4*)(htrow1 + k0 + 4);
        short8 af0, af1;
        af0[0] = (short)f2bf(gelu_fast(a00.x + h0.x));
        af0[1] = (short)f2bf(gelu_fast(a00.y + h0.y));
        af0[2] = (short)f2bf(gelu_fast(a00.z + h0.z));
        af0[3] = (short)f2bf(gelu_fast(a00.w + h0.w));
        af0[4] = (short)f2bf(gelu_fast(a01.x + h1.x));
        af0[5] = (short)f2bf(gelu_fast(a01.y + h1.y));
        af0[6] = (short)f2bf(gelu_fast(a01.z + h1.z));
        af0[7] = (short)f2bf(gelu_fast(a01.w + h1.w));
        af1[0] = (short)f2bf(gelu_fast(a10.x + h0.x));
        af1[1] = (short)f2bf(gelu_fast(a10.y + h0.y));
        af1[2] = (short)f2bf(gelu_fast(a10.z + h0.z));
        af1[3] = (short)f2bf(gelu_fast(a10.w + h0.w));
        af1[4] = (short)f2bf(gelu_fast(a11.x + h1.x));
        af1[5] = (short)f2bf(gelu_fast(a11.y + h1.y));
        af1[6] = (short)f2bf(gelu_fast(a11.z + h1.z));
        af1[7] = (short)f2bf(gelu_fast(a11.w + h1.w));
        #pragma unroll
        for (int nt = 0; nt < 8; nt++) {
            short8 bf = *(const short8*)(&w2s[nt * 16 + l16][k0]);
            acc[0][nt] = __builtin_amdgcn_mfma_f32_16x16x32_bf16(af0, bf, acc[0][nt], 0, 0, 0);
            acc[1][nt] = __builtin_amdgcn_mfma_f32_16x16x32_bf16(af1, bf, acc[1][nt], 0, 0, 0);
        }
    }

    // epilogue: +b2, gelu, *W3, reduce over 128 cols per row, +b3
    const float b3v = b3[0];
    float psum[2][4] = {{0.f, 0.f, 0.f, 0.f}, {0.f, 0.f, 0.f, 0.f}};
    #pragma unroll
    for (int nt = 0; nt < 8; nt++) {
        const int n = nt * 16 + l16;
        const float bb = b2_s[n];
        const float ww = w3_s[n];
        #pragma unroll
        for (int m = 0; m < 2; m++)
            #pragma unroll
            for (int r = 0; r < 4; r++)
                psum[m][r] += gelu_fast(acc[m][nt][r] + bb) * ww;
    }
    #pragma unroll
    for (int s = 8; s >= 1; s >>= 1) {
        #pragma unroll
        for (int m = 0; m < 2; m++)
            #pragma unroll
            for (int r = 0; r < 4; r++)
                psum[m][r] += __shfl_xor(psum[m][r], s, 64);
    }
    if (l16 == 0) {
        #pragma unroll
        for (int m = 0; m < 2; m++) {
            const int rowb = t0 + wave * 32 + m * 16 + quad * 4;
            float4 o = make_float4(psum[m][0] + b3v, psum[m][1] + b3v,
                                   psum[m][2] + b3v, psum[m][3] + b3v);
            *(float4*)(out + (size_t)((b << 7) + u) * T_ + rowb) = o;
        }
    }
}

extern "C" void kernel_launch(void* const* d_in, const int* in_sizes, int n_in,
                              void* d_out, int out_size, void* d_ws, size_t ws_size,
                              hipStream_t stream)
{
    const float* ue = (const float*)d_in[0];
    const float* te = (const float*)d_in[1];
    const float* ge = (const float*)d_in[2];
    const float* W1 = (const float*)d_in[3];
    const float* b1 = (const float*)d_in[4];
    const float* W2 = (const float*)d_in[5];
    const float* b2 = (const float*)d_in[6];
    const float* W3 = (const float*)d_in[7];
    const float* b3 = (const float*)d_in[8];
    float* out = (float*)d_out;

    char* ws = (char*)d_ws;
    float* hu_ws = (float*)ws;                                    // 512 KB
    float* ht_ws = (float*)(ws + 512 * 1024);                     // 1 MB
    unsigned short* w2t_ws = (unsigned short*)(ws + 1536 * 1024); // 32 KB
    float* gu_ws = (float*)(ws + 1568 * 1024);                    // 4 KB

    stage1_kernel<<<dim3(36), dim3(256), 0, stream>>>(
        ue, te, ge, W1, b1, W2, hu_ws, ht_ws, gu_ws, w2t_ws);
    stage2_kernel<<<dim3(T_ / 128, U_, B_), dim3(256), 0, stream>>>(
        hu_ws, ht_ws, gu_ws, w2t_ws, b2, W3, b3, out);
}